// Round 5
// baseline (147.713 us; speedup 1.0000x reference)
//
#include <hip/hip_runtime.h>

#define NCLS 7

// ws layout (4-byte slots):
//   [0] int   anchor        [1] int   a_cls
//   [2] float pos_num       [3] float neg_num
//   [4] float inv_norm(anc_t) [5] inv_norm(anc_v) [6] inv_norm(anc_a)
//   [7]  pad
//   [8]  int  tail counter (zeroed by prep each call)
//   [9..15] pad
//   [16..]   per-row partials: float2 (pos, neg)
struct Hdr {
    int   anchor;
    int   a_cls;
    float pos_num;
    float neg_num;
    float inv_at;
    float inv_av;
    float inv_aa;
    int   pad;
};

__device__ __forceinline__ float dot4(float4 a, float4 b) {
    return a.x * b.x + a.y * b.y + a.z * b.z + a.w * b.w;
}

// ---------------------------------------------------------------------------
// Kernel A (1024 thr): one pass over labels, per-thread register histogram +
// per-class min index (no atomics), int4 loads; then 12 waves compute the 3
// anchor-row inverse norms (4 waves per row). Also zeroes the tail counter.
// ---------------------------------------------------------------------------
__global__ __launch_bounds__(1024) void prep_kernel(
    const int* __restrict__ label,
    const float* __restrict__ s_t,
    const float* __restrict__ s_v,
    const float* __restrict__ s_a,
    int B, int D, float* __restrict__ ws)
{
    const int tid  = threadIdx.x;
    const int w    = tid >> 6;
    const int lane = tid & 63;

    int cnt[NCLS];
    int mn[NCLS];
#pragma unroll
    for (int k = 0; k < NCLS; ++k) { cnt[k] = 0; mn[k] = 0x7fffffff; }

    const int4* lab4 = (const int4*)label;
    const int n4 = B >> 2;
    for (int j = tid; j < n4; j += 1024) {
        int4 L = lab4[j];
        const int base = j << 2;
        int ls[4] = { L.x, L.y, L.z, L.w };
#pragma unroll
        for (int e = 0; e < 4; ++e) {
#pragma unroll
            for (int k = 0; k < NCLS; ++k) {
                if (ls[e] == k) { cnt[k]++; mn[k] = min(mn[k], base + e); }
            }
        }
    }
    for (int i = (n4 << 2) + tid; i < B; i += 1024) {
        int l = label[i];
#pragma unroll
        for (int k = 0; k < NCLS; ++k)
            if (l == k) { cnt[k]++; mn[k] = min(mn[k], i); }
    }

#pragma unroll
    for (int k = 0; k < NCLS; ++k) {
        for (int off = 32; off; off >>= 1) {
            cnt[k] += __shfl_xor(cnt[k], off);
            mn[k]   = min(mn[k], __shfl_xor(mn[k], off));
        }
    }

    __shared__ int   s_cnt[16][NCLS], s_mn[16][NCLS];
    __shared__ int   s_anchor;
    __shared__ float s_norm[12];
    if (lane == 0) {
#pragma unroll
        for (int k = 0; k < NCLS; ++k) { s_cnt[w][k] = cnt[k]; s_mn[w][k] = mn[k]; }
    }
    __syncthreads();

    if (tid == 0) {
        int hist[NCLS], mini[NCLS];
#pragma unroll
        for (int k = 0; k < NCLS; ++k) {
            int hc = 0, mc = 0x7fffffff;
            for (int q = 0; q < 16; ++q) { hc += s_cnt[q][k]; mc = min(mc, s_mn[q][k]); }
            hist[k] = hc; mini[k] = mc;
        }
        // jnp.argmax(counts > 1): first class with count>1, else 0
        int c = 0;
#pragma unroll
        for (int k = NCLS - 1; k >= 0; --k) if (hist[k] > 1) c = k;
        s_anchor = mini[c];

        Hdr* h = (Hdr*)ws;
        h->anchor  = mini[c];
        h->a_cls   = c;
        float pn   = (float)hist[c];
        h->pos_num = pn;
        h->neg_num = (float)B - pn;
        ((int*)ws)[8] = 0;            // tail counter for fused reduction
    }
    __syncthreads();

    const int anchor = s_anchor;
    if (w < 12) {
        const int rw = w >> 2, qw = w & 3;
        const float* src = (rw == 0) ? s_t : (rw == 1) ? s_v : s_a;
        const float4* row = (const float4*)(src + (size_t)anchor * D);
        const int nvec = D >> 2;
        float s = 0.f;
        for (int j = qw * 64 + lane; j < nvec; j += 256) {
            float4 x = row[j];
            s += dot4(x, x);
        }
        for (int off = 32; off; off >>= 1) s += __shfl_xor(s, off);
        if (lane == 0) s_norm[w] = s;
    }
    __syncthreads();
    if (tid < 3)
        ((float*)ws)[4 + tid] = rsqrtf(s_norm[4 * tid] + s_norm[4 * tid + 1] +
                                       s_norm[4 * tid + 2] + s_norm[4 * tid + 3]);
}

// ---------------------------------------------------------------------------
// Kernel B: TWO ROWS PER BLOCK. Each thread: 9 independent float4 loads
// (2x3 streaming rows + 3 anchor, amortized over both rows), 15 dot4s.
// Reduction: stage 1 reduces the 6 row sum-of-squares, broadcasts inv norms;
// stage 2 folds each row's 6 partial dots into one scalar (linearity) and a
// single reduce finishes each row. Tail: last-block-done counter; the last
// block reduces all B partials in fixed order (deterministic) -> out.
// ---------------------------------------------------------------------------
__global__ __launch_bounds__(256) void main_kernel(
    const int* __restrict__ label,
    const float* __restrict__ s_t,
    const float* __restrict__ s_v,
    const float* __restrict__ s_a,
    int B, int D, float* __restrict__ ws, float* __restrict__ out)
{
    const Hdr* h = (const Hdr*)ws;
    float2* partials = (float2*)(ws + 16);
    int* counter = (int*)ws + 8;

    const int tid  = threadIdx.x;
    const int w    = tid >> 6;
    const int lane = tid & 63;

    const int r0 = blockIdx.x * 2;
    const int r1 = r0 + 1;

    const int lab0 = label[r0];
    const int lab1 = label[r1];
    const int anchor = h->anchor;

    const float4* rt0 = (const float4*)(s_t + (size_t)r0 * D);
    const float4* rv0 = (const float4*)(s_v + (size_t)r0 * D);
    const float4* ra0 = (const float4*)(s_a + (size_t)r0 * D);
    const float4* rt1 = (const float4*)(s_t + (size_t)r1 * D);
    const float4* rv1 = (const float4*)(s_v + (size_t)r1 * D);
    const float4* ra1 = (const float4*)(s_a + (size_t)r1 * D);
    const float4* at  = (const float4*)(s_t + (size_t)anchor * D);
    const float4* av  = (const float4*)(s_v + (size_t)anchor * D);
    const float4* aa  = (const float4*)(s_a + (size_t)anchor * D);

    // D = 1024 -> nvec = 256 -> exactly one float4 per thread per stream.
    // (loop kept for generality; single iteration for the bench shape)
    float dt_a0 = 0.f, dt_v0 = 0.f, sq_t0 = 0.f;
    float dv_t0 = 0.f, dv_a0 = 0.f, sq_v0 = 0.f;
    float da_t0 = 0.f, da_v0 = 0.f, sq_a0 = 0.f;
    float dt_a1 = 0.f, dt_v1 = 0.f, sq_t1 = 0.f;
    float dv_t1 = 0.f, dv_a1 = 0.f, sq_v1 = 0.f;
    float da_t1 = 0.f, da_v1 = 0.f, sq_a1 = 0.f;

    const int nvec = D >> 2;
    for (int j = tid; j < nvec; j += 256) {
        float4 bt = at[j], bv = av[j], ba = aa[j];
        float4 t0 = rt0[j], v0 = rv0[j], a0 = ra0[j];
        float4 t1 = rt1[j], v1 = rv1[j], a1 = ra1[j];

        dt_a0 += dot4(t0, ba);  dt_v0 += dot4(t0, bv);  sq_t0 += dot4(t0, t0);
        dv_t0 += dot4(v0, bt);  dv_a0 += dot4(v0, ba);  sq_v0 += dot4(v0, v0);
        da_t0 += dot4(a0, bt);  da_v0 += dot4(a0, bv);  sq_a0 += dot4(a0, a0);

        dt_a1 += dot4(t1, ba);  dt_v1 += dot4(t1, bv);  sq_t1 += dot4(t1, t1);
        dv_t1 += dot4(v1, bt);  dv_a1 += dot4(v1, ba);  sq_v1 += dot4(v1, v1);
        da_t1 += dot4(a1, bt);  da_v1 += dot4(a1, bv);  sq_a1 += dot4(a1, a1);
    }

    // --- stage 1: block-reduce the six sum-of-squares, broadcast ---
    for (int off = 32; off; off >>= 1) {
        sq_t0 += __shfl_xor(sq_t0, off);
        sq_v0 += __shfl_xor(sq_v0, off);
        sq_a0 += __shfl_xor(sq_a0, off);
        sq_t1 += __shfl_xor(sq_t1, off);
        sq_v1 += __shfl_xor(sq_v1, off);
        sq_a1 += __shfl_xor(sq_a1, off);
    }
    __shared__ float red_sq[4][6];
    __shared__ float red_c[4][2];
    if (lane == 0) {
        red_sq[w][0] = sq_t0; red_sq[w][1] = sq_v0; red_sq[w][2] = sq_a0;
        red_sq[w][3] = sq_t1; red_sq[w][4] = sq_v1; red_sq[w][5] = sq_a1;
    }
    __syncthreads();

    const float inv_t0 = rsqrtf(red_sq[0][0] + red_sq[1][0] + red_sq[2][0] + red_sq[3][0]);
    const float inv_v0 = rsqrtf(red_sq[0][1] + red_sq[1][1] + red_sq[2][1] + red_sq[3][1]);
    const float inv_a0 = rsqrtf(red_sq[0][2] + red_sq[1][2] + red_sq[2][2] + red_sq[3][2]);
    const float inv_t1 = rsqrtf(red_sq[0][3] + red_sq[1][3] + red_sq[2][3] + red_sq[3][3]);
    const float inv_v1 = rsqrtf(red_sq[0][4] + red_sq[1][4] + red_sq[2][4] + red_sq[3][4]);
    const float inv_a1 = rsqrtf(red_sq[0][5] + red_sq[1][5] + red_sq[2][5] + red_sq[3][5]);

    // --- stage 2: fold each row's 6 partial dots into one scalar ---
    float c0 = inv_t0 * (dt_a0 * h->inv_aa + dt_v0 * h->inv_av)
             + inv_v0 * (dv_t0 * h->inv_at + dv_a0 * h->inv_aa)
             + inv_a0 * (da_t0 * h->inv_at + da_v0 * h->inv_av);
    float c1 = inv_t1 * (dt_a1 * h->inv_aa + dt_v1 * h->inv_av)
             + inv_v1 * (dv_t1 * h->inv_at + dv_a1 * h->inv_aa)
             + inv_a1 * (da_t1 * h->inv_at + da_v1 * h->inv_av);

    for (int off = 32; off; off >>= 1) {
        c0 += __shfl_xor(c0, off);
        c1 += __shfl_xor(c1, off);
    }
    if (lane == 0) { red_c[w][0] = c0; red_c[w][1] = c1; }
    __syncthreads();

    __shared__ int s_isLast;
    if (tid < 2) {
        float rowtot = red_c[0][tid] + red_c[1][tid] + red_c[2][tid] + red_c[3][tid];
        const int r   = r0 + tid;
        const int lab = tid ? lab1 : lab0;
        bool isPos = (lab == h->a_cls) && (r != anchor);
        bool isNeg = (lab != h->a_cls);
        partials[r] = make_float2(isPos ? rowtot : 0.f, isNeg ? rowtot : 0.f);
    }
    __syncthreads();
    if (tid == 0) {
        __threadfence();                      // release partials (device scope)
        int old = atomicAdd(counter, 1);
        s_isLast = (old == (int)gridDim.x - 1);
    }
    __syncthreads();

    if (s_isLast) {
        __threadfence();                      // acquire other blocks' partials
        volatile float* pf = (volatile float*)partials;
        float p = 0.f, n = 0.f;
        for (int i = tid; i < B; i += 256) {
            p += pf[2 * i];
            n += pf[2 * i + 1];
        }
        for (int off = 32; off; off >>= 1) {
            p += __shfl_xor(p, off);
            n += __shfl_xor(n, off);
        }
        __shared__ float pp[4], nn[4];
        if (lane == 0) { pp[w] = p; nn[w] = n; }
        __syncthreads();
        if (tid == 0) {
            float P = pp[0] + pp[1] + pp[2] + pp[3];
            float N = nn[0] + nn[1] + nn[2] + nn[3];
            out[0] = (6.0f - P / h->pos_num + N / h->neg_num) / 3.0f;
        }
    }
}

extern "C" void kernel_launch(void* const* d_in, const int* in_sizes, int n_in,
                              void* d_out, int out_size, void* d_ws, size_t ws_size,
                              hipStream_t stream) {
    const int*   label = (const int*)d_in[0];
    const float* s_t   = (const float*)d_in[1];
    const float* s_v   = (const float*)d_in[2];
    const float* s_a   = (const float*)d_in[3];

    const int B = in_sizes[0];
    const int D = in_sizes[1] / B;   // 1024

    float* ws  = (float*)d_ws;
    float* out = (float*)d_out;

    const int nblocks = B / 2;       // two rows per block

    prep_kernel<<<1, 1024, 0, stream>>>(label, s_t, s_v, s_a, B, D, ws);
    main_kernel<<<nblocks, 256, 0, stream>>>(label, s_t, s_v, s_a, B, D, ws, out);
}

// Round 6
// 35.730 us; speedup vs baseline: 4.1341x; 4.1341x over previous
//
#include <hip/hip_runtime.h>

#define NCLS 7

// ws layout (4-byte slots):
//   [0] int   anchor        [1] int   a_cls
//   [2] float pos_num       [3] float neg_num
//   [4] float inv_norm(anc_t) [5] inv_norm(anc_v) [6] inv_norm(anc_a)
//   [7..15] pad
//   [16..]   per-row partials: float2 (pos, neg)
struct Hdr {
    int   anchor;
    int   a_cls;
    float pos_num;
    float neg_num;
    float inv_at;
    float inv_av;
    float inv_aa;
    int   pad;
};

__device__ __forceinline__ float dot4(float4 a, float4 b) {
    return a.x * b.x + a.y * b.y + a.z * b.z + a.w * b.w;
}

// ---------------------------------------------------------------------------
// Kernel A (1024 thr): one pass over labels, per-thread register histogram +
// per-class min index (no atomics), int4 loads; then 12 waves compute the 3
// anchor-row inverse norms (4 waves per row).
// ---------------------------------------------------------------------------
__global__ __launch_bounds__(1024) void prep_kernel(
    const int* __restrict__ label,
    const float* __restrict__ s_t,
    const float* __restrict__ s_v,
    const float* __restrict__ s_a,
    int B, int D, float* __restrict__ ws)
{
    const int tid  = threadIdx.x;
    const int w    = tid >> 6;
    const int lane = tid & 63;

    int cnt[NCLS];
    int mn[NCLS];
#pragma unroll
    for (int k = 0; k < NCLS; ++k) { cnt[k] = 0; mn[k] = 0x7fffffff; }

    const int4* lab4 = (const int4*)label;
    const int n4 = B >> 2;
    for (int j = tid; j < n4; j += 1024) {
        int4 L = lab4[j];
        const int base = j << 2;
        int ls[4] = { L.x, L.y, L.z, L.w };
#pragma unroll
        for (int e = 0; e < 4; ++e) {
#pragma unroll
            for (int k = 0; k < NCLS; ++k) {
                if (ls[e] == k) { cnt[k]++; mn[k] = min(mn[k], base + e); }
            }
        }
    }
    for (int i = (n4 << 2) + tid; i < B; i += 1024) {
        int l = label[i];
#pragma unroll
        for (int k = 0; k < NCLS; ++k)
            if (l == k) { cnt[k]++; mn[k] = min(mn[k], i); }
    }

#pragma unroll
    for (int k = 0; k < NCLS; ++k) {
        for (int off = 32; off; off >>= 1) {
            cnt[k] += __shfl_xor(cnt[k], off);
            mn[k]   = min(mn[k], __shfl_xor(mn[k], off));
        }
    }

    __shared__ int   s_cnt[16][NCLS], s_mn[16][NCLS];
    __shared__ int   s_anchor;
    __shared__ float s_norm[12];
    if (lane == 0) {
#pragma unroll
        for (int k = 0; k < NCLS; ++k) { s_cnt[w][k] = cnt[k]; s_mn[w][k] = mn[k]; }
    }
    __syncthreads();

    if (tid == 0) {
        int hist[NCLS], mini[NCLS];
#pragma unroll
        for (int k = 0; k < NCLS; ++k) {
            int hc = 0, mc = 0x7fffffff;
            for (int q = 0; q < 16; ++q) { hc += s_cnt[q][k]; mc = min(mc, s_mn[q][k]); }
            hist[k] = hc; mini[k] = mc;
        }
        // jnp.argmax(counts > 1): first class with count>1, else 0
        int c = 0;
#pragma unroll
        for (int k = NCLS - 1; k >= 0; --k) if (hist[k] > 1) c = k;
        s_anchor = mini[c];

        Hdr* h = (Hdr*)ws;
        h->anchor  = mini[c];
        h->a_cls   = c;
        float pn   = (float)hist[c];
        h->pos_num = pn;
        h->neg_num = (float)B - pn;
    }
    __syncthreads();

    const int anchor = s_anchor;
    if (w < 12) {
        const int rw = w >> 2, qw = w & 3;
        const float* src = (rw == 0) ? s_t : (rw == 1) ? s_v : s_a;
        const float4* row = (const float4*)(src + (size_t)anchor * D);
        const int nvec = D >> 2;
        float s = 0.f;
        for (int j = qw * 64 + lane; j < nvec; j += 256) {
            float4 x = row[j];
            s += dot4(x, x);
        }
        for (int off = 32; off; off >>= 1) s += __shfl_xor(s, off);
        if (lane == 0) s_norm[w] = s;
    }
    __syncthreads();
    if (tid < 3)
        ((float*)ws)[4 + tid] = rsqrtf(s_norm[4 * tid] + s_norm[4 * tid + 1] +
                                       s_norm[4 * tid + 2] + s_norm[4 * tid + 3]);
}

// ---------------------------------------------------------------------------
// Kernel B: TWO ROWS PER BLOCK, no fences, no atomics (round-5 post-mortem:
// per-block device-scope fence invalidates the XCD's L2 -> 6x regression).
// Each thread: 9 independent float4 loads (3 anchor amortized over 2 rows),
// 15 dot4s. launch_bounds(256,4) caps VGPR at 128 so all 9 loads stay in
// flight (round-5's VGPR=40 serialized them). 4-family reduction as before.
// ---------------------------------------------------------------------------
__global__ __launch_bounds__(256, 4) void main_kernel(
    const int* __restrict__ label,
    const float* __restrict__ s_t,
    const float* __restrict__ s_v,
    const float* __restrict__ s_a,
    int B, int D, float* __restrict__ ws)
{
    const Hdr* h = (const Hdr*)ws;
    float2* partials = (float2*)(ws + 16);

    const int tid  = threadIdx.x;
    const int w    = tid >> 6;
    const int lane = tid & 63;

    const int r0 = blockIdx.x * 2;
    const int r1 = r0 + 1;

    const int lab0 = label[r0];
    const int lab1 = label[r1];
    const int anchor = h->anchor;

    const float4* rt0 = (const float4*)(s_t + (size_t)r0 * D);
    const float4* rv0 = (const float4*)(s_v + (size_t)r0 * D);
    const float4* ra0 = (const float4*)(s_a + (size_t)r0 * D);
    const float4* rt1 = (const float4*)(s_t + (size_t)r1 * D);
    const float4* rv1 = (const float4*)(s_v + (size_t)r1 * D);
    const float4* ra1 = (const float4*)(s_a + (size_t)r1 * D);
    const float4* at  = (const float4*)(s_t + (size_t)anchor * D);
    const float4* av  = (const float4*)(s_v + (size_t)anchor * D);
    const float4* aa  = (const float4*)(s_a + (size_t)anchor * D);

    float dt_a0 = 0.f, dt_v0 = 0.f, sq_t0 = 0.f;
    float dv_t0 = 0.f, dv_a0 = 0.f, sq_v0 = 0.f;
    float da_t0 = 0.f, da_v0 = 0.f, sq_a0 = 0.f;
    float dt_a1 = 0.f, dt_v1 = 0.f, sq_t1 = 0.f;
    float dv_t1 = 0.f, dv_a1 = 0.f, sq_v1 = 0.f;
    float da_t1 = 0.f, da_v1 = 0.f, sq_a1 = 0.f;

    const int nvec = D >> 2;          // 256 for D=1024 -> one iter per thread
    for (int j = tid; j < nvec; j += 256) {
        float4 bt = at[j], bv = av[j], ba = aa[j];
        float4 t0 = rt0[j], v0 = rv0[j], a0 = ra0[j];
        float4 t1 = rt1[j], v1 = rv1[j], a1 = ra1[j];

        dt_a0 += dot4(t0, ba);  dt_v0 += dot4(t0, bv);  sq_t0 += dot4(t0, t0);
        dv_t0 += dot4(v0, bt);  dv_a0 += dot4(v0, ba);  sq_v0 += dot4(v0, v0);
        da_t0 += dot4(a0, bt);  da_v0 += dot4(a0, bv);  sq_a0 += dot4(a0, a0);

        dt_a1 += dot4(t1, ba);  dt_v1 += dot4(t1, bv);  sq_t1 += dot4(t1, t1);
        dv_t1 += dot4(v1, bt);  dv_a1 += dot4(v1, ba);  sq_v1 += dot4(v1, v1);
        da_t1 += dot4(a1, bt);  da_v1 += dot4(a1, bv);  sq_a1 += dot4(a1, a1);
    }

    // --- stage 1: block-reduce the six sum-of-squares, broadcast ---
    for (int off = 32; off; off >>= 1) {
        sq_t0 += __shfl_xor(sq_t0, off);
        sq_v0 += __shfl_xor(sq_v0, off);
        sq_a0 += __shfl_xor(sq_a0, off);
        sq_t1 += __shfl_xor(sq_t1, off);
        sq_v1 += __shfl_xor(sq_v1, off);
        sq_a1 += __shfl_xor(sq_a1, off);
    }
    __shared__ float red_sq[4][6];
    __shared__ float red_c[4][2];
    if (lane == 0) {
        red_sq[w][0] = sq_t0; red_sq[w][1] = sq_v0; red_sq[w][2] = sq_a0;
        red_sq[w][3] = sq_t1; red_sq[w][4] = sq_v1; red_sq[w][5] = sq_a1;
    }
    __syncthreads();

    const float inv_t0 = rsqrtf(red_sq[0][0] + red_sq[1][0] + red_sq[2][0] + red_sq[3][0]);
    const float inv_v0 = rsqrtf(red_sq[0][1] + red_sq[1][1] + red_sq[2][1] + red_sq[3][1]);
    const float inv_a0 = rsqrtf(red_sq[0][2] + red_sq[1][2] + red_sq[2][2] + red_sq[3][2]);
    const float inv_t1 = rsqrtf(red_sq[0][3] + red_sq[1][3] + red_sq[2][3] + red_sq[3][3]);
    const float inv_v1 = rsqrtf(red_sq[0][4] + red_sq[1][4] + red_sq[2][4] + red_sq[3][4]);
    const float inv_a1 = rsqrtf(red_sq[0][5] + red_sq[1][5] + red_sq[2][5] + red_sq[3][5]);

    // --- stage 2: fold each row's 6 partial dots into one scalar ---
    float c0 = inv_t0 * (dt_a0 * h->inv_aa + dt_v0 * h->inv_av)
             + inv_v0 * (dv_t0 * h->inv_at + dv_a0 * h->inv_aa)
             + inv_a0 * (da_t0 * h->inv_at + da_v0 * h->inv_av);
    float c1 = inv_t1 * (dt_a1 * h->inv_aa + dt_v1 * h->inv_av)
             + inv_v1 * (dv_t1 * h->inv_at + dv_a1 * h->inv_aa)
             + inv_a1 * (da_t1 * h->inv_at + da_v1 * h->inv_av);

    for (int off = 32; off; off >>= 1) {
        c0 += __shfl_xor(c0, off);
        c1 += __shfl_xor(c1, off);
    }
    if (lane == 0) { red_c[w][0] = c0; red_c[w][1] = c1; }
    __syncthreads();

    if (tid < 2) {
        float rowtot = red_c[0][tid] + red_c[1][tid] + red_c[2][tid] + red_c[3][tid];
        const int r   = r0 + tid;
        const int lab = tid ? lab1 : lab0;
        bool isPos = (lab == h->a_cls) && (r != anchor);
        bool isNeg = (lab != h->a_cls);
        partials[r] = make_float2(isPos ? rowtot : 0.f, isNeg ? rowtot : 0.f);
    }
}

// ---------------------------------------------------------------------------
// Kernel C: deterministic reduction of B partial pairs -> scalar loss.
// loss = (6 - pos_total/pos_num + neg_total/neg_num) / 3
// ---------------------------------------------------------------------------
__global__ __launch_bounds__(1024) void finish_kernel(
    const float* __restrict__ ws, int B, float* __restrict__ out)
{
    const Hdr* h = (const Hdr*)ws;
    const float2* partials = (const float2*)(ws + 16);

    float p = 0.f, n = 0.f;
    for (int i = threadIdx.x; i < B; i += 1024) {
        float2 pr = partials[i];
        p += pr.x;
        n += pr.y;
    }
    for (int off = 32; off; off >>= 1) {
        p += __shfl_xor(p, off);
        n += __shfl_xor(n, off);
    }
    __shared__ float pp[16], nn[16];
    const int w = threadIdx.x >> 6, lane = threadIdx.x & 63;
    if (lane == 0) { pp[w] = p; nn[w] = n; }
    __syncthreads();
    if (threadIdx.x == 0) {
        float P = 0.f, N = 0.f;
#pragma unroll
        for (int k = 0; k < 16; ++k) { P += pp[k]; N += nn[k]; }
        out[0] = (6.0f - P / h->pos_num + N / h->neg_num) / 3.0f;
    }
}

extern "C" void kernel_launch(void* const* d_in, const int* in_sizes, int n_in,
                              void* d_out, int out_size, void* d_ws, size_t ws_size,
                              hipStream_t stream) {
    const int*   label = (const int*)d_in[0];
    const float* s_t   = (const float*)d_in[1];
    const float* s_v   = (const float*)d_in[2];
    const float* s_a   = (const float*)d_in[3];

    const int B = in_sizes[0];
    const int D = in_sizes[1] / B;   // 1024

    float* ws  = (float*)d_ws;
    float* out = (float*)d_out;

    const int nblocks = B / 2;       // two rows per block

    prep_kernel<<<1, 1024, 0, stream>>>(label, s_t, s_v, s_a, B, D, ws);
    main_kernel<<<nblocks, 256, 0, stream>>>(label, s_t, s_v, s_a, B, D, ws);
    finish_kernel<<<1, 1024, 0, stream>>>(ws, B, out);
}

// Round 7
// 33.304 us; speedup vs baseline: 4.4353x; 1.0728x over previous
//
#include <hip/hip_runtime.h>

#define NCLS 7

// ws layout (4-byte slots):
//   [0] int   anchor        [1] int   a_cls
//   [2] float pos_num       [3] float neg_num
//   [4] float inv_norm(anc_t) [5] inv_norm(anc_v) [6] inv_norm(anc_a)
//   [7..15] pad
//   [16..]   per-row partials: float2 (pos, neg)
struct Hdr {
    int   anchor;
    int   a_cls;
    float pos_num;
    float neg_num;
    float inv_at;
    float inv_av;
    float inv_aa;
    int   pad;
};

__device__ __forceinline__ float dot4(float4 a, float4 b) {
    return a.x * b.x + a.y * b.y + a.z * b.z + a.w * b.w;
}

// Wave64 sum via DPP (VALU pipe only — no DS ops, no LDS):
// row_shr 1/2/4/8 (zero-fill) -> lane15/31/47/63 hold their row-of-16 sums;
// row_bcast15 (rows 1,3) -> lane31 = rows0-1, lane63 = rows2-3;
// row_bcast31 (rows 2,3) -> lane63 = full wave sum; readlane 63 broadcasts.
__device__ __forceinline__ float wave_sum_dpp(float x) {
    float t;
    t = __int_as_float(__builtin_amdgcn_update_dpp(0, __float_as_int(x), 0x111, 0xf, 0xf, true));  x += t;
    t = __int_as_float(__builtin_amdgcn_update_dpp(0, __float_as_int(x), 0x112, 0xf, 0xf, true));  x += t;
    t = __int_as_float(__builtin_amdgcn_update_dpp(0, __float_as_int(x), 0x114, 0xf, 0xf, true));  x += t;
    t = __int_as_float(__builtin_amdgcn_update_dpp(0, __float_as_int(x), 0x118, 0xf, 0xf, true));  x += t;
    t = __int_as_float(__builtin_amdgcn_update_dpp(0, __float_as_int(x), 0x142, 0xa, 0xf, false)); x += t;
    t = __int_as_float(__builtin_amdgcn_update_dpp(0, __float_as_int(x), 0x143, 0xc, 0xf, false)); x += t;
    return __int_as_float(__builtin_amdgcn_readlane(__float_as_int(x), 63));
}

// ---------------------------------------------------------------------------
// Kernel A (1024 thr): one pass over labels, per-thread register histogram +
// per-class min index (no atomics), int4 loads; then 12 waves compute the 3
// anchor-row inverse norms (4 waves per row).
// ---------------------------------------------------------------------------
__global__ __launch_bounds__(1024) void prep_kernel(
    const int* __restrict__ label,
    const float* __restrict__ s_t,
    const float* __restrict__ s_v,
    const float* __restrict__ s_a,
    int B, int D, float* __restrict__ ws)
{
    const int tid  = threadIdx.x;
    const int w    = tid >> 6;
    const int lane = tid & 63;

    int cnt[NCLS];
    int mn[NCLS];
#pragma unroll
    for (int k = 0; k < NCLS; ++k) { cnt[k] = 0; mn[k] = 0x7fffffff; }

    const int4* lab4 = (const int4*)label;
    const int n4 = B >> 2;
    for (int j = tid; j < n4; j += 1024) {
        int4 L = lab4[j];
        const int base = j << 2;
        int ls[4] = { L.x, L.y, L.z, L.w };
#pragma unroll
        for (int e = 0; e < 4; ++e) {
#pragma unroll
            for (int k = 0; k < NCLS; ++k) {
                if (ls[e] == k) { cnt[k]++; mn[k] = min(mn[k], base + e); }
            }
        }
    }
    for (int i = (n4 << 2) + tid; i < B; i += 1024) {
        int l = label[i];
#pragma unroll
        for (int k = 0; k < NCLS; ++k)
            if (l == k) { cnt[k]++; mn[k] = min(mn[k], i); }
    }

#pragma unroll
    for (int k = 0; k < NCLS; ++k) {
        for (int off = 32; off; off >>= 1) {
            cnt[k] += __shfl_xor(cnt[k], off);
            mn[k]   = min(mn[k], __shfl_xor(mn[k], off));
        }
    }

    __shared__ int   s_cnt[16][NCLS], s_mn[16][NCLS];
    __shared__ int   s_anchor;
    __shared__ float s_norm[12];
    if (lane == 0) {
#pragma unroll
        for (int k = 0; k < NCLS; ++k) { s_cnt[w][k] = cnt[k]; s_mn[w][k] = mn[k]; }
    }
    __syncthreads();

    if (tid == 0) {
        int hist[NCLS], mini[NCLS];
#pragma unroll
        for (int k = 0; k < NCLS; ++k) {
            int hc = 0, mc = 0x7fffffff;
            for (int q = 0; q < 16; ++q) { hc += s_cnt[q][k]; mc = min(mc, s_mn[q][k]); }
            hist[k] = hc; mini[k] = mc;
        }
        // jnp.argmax(counts > 1): first class with count>1, else 0
        int c = 0;
#pragma unroll
        for (int k = NCLS - 1; k >= 0; --k) if (hist[k] > 1) c = k;
        s_anchor = mini[c];

        Hdr* h = (Hdr*)ws;
        h->anchor  = mini[c];
        h->a_cls   = c;
        float pn   = (float)hist[c];
        h->pos_num = pn;
        h->neg_num = (float)B - pn;
    }
    __syncthreads();

    const int anchor = s_anchor;
    if (w < 12) {
        const int rw = w >> 2, qw = w & 3;
        const float* src = (rw == 0) ? s_t : (rw == 1) ? s_v : s_a;
        const float4* row = (const float4*)(src + (size_t)anchor * D);
        const int nvec = D >> 2;
        float s = 0.f;
        for (int j = qw * 64 + lane; j < nvec; j += 256) {
            float4 x = row[j];
            s += dot4(x, x);
        }
        for (int off = 32; off; off >>= 1) s += __shfl_xor(s, off);
        if (lane == 0) s_norm[w] = s;
    }
    __syncthreads();
    if (tid < 3)
        ((float*)ws)[4 + tid] = rsqrtf(s_norm[4 * tid] + s_norm[4 * tid + 1] +
                                       s_norm[4 * tid + 2] + s_norm[4 * tid + 3]);
}

// ---------------------------------------------------------------------------
// Kernel B: ONE WAVE PER ROW — zero LDS, zero barriers, zero DS-pipe ops.
// Per lane (D=1024 path): 24 independent float4 loads fully unrolled,
// 36 dot4s, then 4 DPP wave-reductions (3 sumsq -> rsqrt broadcast via
// readlane -> per-lane linear fold -> 1 final DPP reduce). Lane 0 writes
// the row's (pos,neg) partial. Waves never wait on each other; the DS pipe
// (the r3->r4 bottleneck) is completely idle.
// ---------------------------------------------------------------------------
__global__ __launch_bounds__(256) void main_kernel(
    const int* __restrict__ label,
    const float* __restrict__ s_t,
    const float* __restrict__ s_v,
    const float* __restrict__ s_a,
    int B, int D, float* __restrict__ ws)
{
    const Hdr* h = (const Hdr*)ws;
    float2* partials = (float2*)(ws + 16);

    const int lane = threadIdx.x & 63;
    const int r    = blockIdx.x * 4 + (threadIdx.x >> 6);   // wave id == row
    if (r >= B) return;

    const int anchor = h->anchor;
    const int lab    = label[r];

    const float4* rt = (const float4*)(s_t + (size_t)r * D);
    const float4* rv = (const float4*)(s_v + (size_t)r * D);
    const float4* ra = (const float4*)(s_a + (size_t)r * D);
    const float4* at = (const float4*)(s_t + (size_t)anchor * D);
    const float4* av = (const float4*)(s_v + (size_t)anchor * D);
    const float4* aa = (const float4*)(s_a + (size_t)anchor * D);

    float dt_a = 0.f, dt_v = 0.f, sq_t = 0.f;
    float dv_t = 0.f, dv_a = 0.f, sq_v = 0.f;
    float da_t = 0.f, da_v = 0.f, sq_a = 0.f;

    const int nvec = D >> 2;
    if (nvec == 256) {
        // D == 1024 fast path: 4 float4 per lane per stream, fully unrolled
        // -> all 24 loads issued before any dependent use.
        float4 T[4], V[4], A[4], BT[4], BV[4], BA[4];
#pragma unroll
        for (int it = 0; it < 4; ++it) {
            const int j = lane + (it << 6);
            T[it]  = rt[j];  V[it]  = rv[j];  A[it]  = ra[j];
            BT[it] = at[j];  BV[it] = av[j];  BA[it] = aa[j];
        }
#pragma unroll
        for (int it = 0; it < 4; ++it) {
            dt_a += dot4(T[it], BA[it]);  dt_v += dot4(T[it], BV[it]);  sq_t += dot4(T[it], T[it]);
            dv_t += dot4(V[it], BT[it]);  dv_a += dot4(V[it], BA[it]);  sq_v += dot4(V[it], V[it]);
            da_t += dot4(A[it], BT[it]);  da_v += dot4(A[it], BV[it]);  sq_a += dot4(A[it], A[it]);
        }
    } else {
        for (int j = lane; j < nvec; j += 64) {
            float4 t  = rt[j], v  = rv[j], a  = ra[j];
            float4 bt = at[j], bv = av[j], ba = aa[j];
            dt_a += dot4(t, ba);  dt_v += dot4(t, bv);  sq_t += dot4(t, t);
            dv_t += dot4(v, bt);  dv_a += dot4(v, ba);  sq_v += dot4(v, v);
            da_t += dot4(a, bt);  da_v += dot4(a, bv);  sq_a += dot4(a, a);
        }
    }

    // 3 DPP reductions for the row norms (VALU pipe, no DS)
    const float inv_t = rsqrtf(wave_sum_dpp(sq_t));
    const float inv_v = rsqrtf(wave_sum_dpp(sq_v));
    const float inv_a = rsqrtf(wave_sum_dpp(sq_a));

    // per-lane linear fold (anchor & row norms enter linearly), 1 final reduce
    float c = inv_t * (dt_a * h->inv_aa + dt_v * h->inv_av)
            + inv_v * (dv_t * h->inv_at + dv_a * h->inv_aa)
            + inv_a * (da_t * h->inv_at + da_v * h->inv_av);
    const float rowtot = wave_sum_dpp(c);

    if (lane == 0) {
        bool isPos = (lab == h->a_cls) && (r != anchor);
        bool isNeg = (lab != h->a_cls);
        partials[r] = make_float2(isPos ? rowtot : 0.f, isNeg ? rowtot : 0.f);
    }
}

// ---------------------------------------------------------------------------
// Kernel C: deterministic reduction of B partial pairs -> scalar loss.
// loss = (6 - pos_total/pos_num + neg_total/neg_num) / 3
// ---------------------------------------------------------------------------
__global__ __launch_bounds__(1024) void finish_kernel(
    const float* __restrict__ ws, int B, float* __restrict__ out)
{
    const Hdr* h = (const Hdr*)ws;
    const float2* partials = (const float2*)(ws + 16);

    float p = 0.f, n = 0.f;
    for (int i = threadIdx.x; i < B; i += 1024) {
        float2 pr = partials[i];
        p += pr.x;
        n += pr.y;
    }
    for (int off = 32; off; off >>= 1) {
        p += __shfl_xor(p, off);
        n += __shfl_xor(n, off);
    }
    __shared__ float pp[16], nn[16];
    const int w = threadIdx.x >> 6, lane = threadIdx.x & 63;
    if (lane == 0) { pp[w] = p; nn[w] = n; }
    __syncthreads();
    if (threadIdx.x == 0) {
        float P = 0.f, N = 0.f;
#pragma unroll
        for (int k = 0; k < 16; ++k) { P += pp[k]; N += nn[k]; }
        out[0] = (6.0f - P / h->pos_num + N / h->neg_num) / 3.0f;
    }
}

extern "C" void kernel_launch(void* const* d_in, const int* in_sizes, int n_in,
                              void* d_out, int out_size, void* d_ws, size_t ws_size,
                              hipStream_t stream) {
    const int*   label = (const int*)d_in[0];
    const float* s_t   = (const float*)d_in[1];
    const float* s_v   = (const float*)d_in[2];
    const float* s_a   = (const float*)d_in[3];

    const int B = in_sizes[0];
    const int D = in_sizes[1] / B;   // 1024

    float* ws  = (float*)d_ws;
    float* out = (float*)d_out;

    const int nblocks = (B + 3) / 4;   // one wave per row, 4 waves per block

    prep_kernel<<<1, 1024, 0, stream>>>(label, s_t, s_v, s_a, B, D, ws);
    main_kernel<<<nblocks, 256, 0, stream>>>(label, s_t, s_v, s_a, B, D, ws);
    finish_kernel<<<1, 1024, 0, stream>>>(ws, B, out);
}

// Round 8
// 30.333 us; speedup vs baseline: 4.8697x; 1.0980x over previous
//
#include <hip/hip_runtime.h>

#define NCLS 7

// ws layout (4-byte slots):
//   [0] int   anchor        [1] int   a_cls
//   [2] float pos_num       [3] float neg_num
//   [4] float inv_norm(anc_t) [5] inv_norm(anc_v) [6] inv_norm(anc_a)
//   [7..15] pad
//   [16..]   per-row partials: float2 (pos, neg)
struct Hdr {
    int   anchor;
    int   a_cls;
    float pos_num;
    float neg_num;
    float inv_at;
    float inv_av;
    float inv_aa;
    int   pad;
};

__device__ __forceinline__ float dot4(float4 a, float4 b) {
    return a.x * b.x + a.y * b.y + a.z * b.z + a.w * b.w;
}

// ---- Wave64 reductions on the VALU pipe via DPP (no DS ops) ---------------
// sum: row_shr 1/2/4/8 (0-fill) -> lane15/31/47/63 hold row-of-16 sums;
// row_bcast15 (rows 1,3), row_bcast31 (rows 2,3) -> lane63 = wave total.
__device__ __forceinline__ float wave_fsum_dpp(float x) {
    float t;
    t = __int_as_float(__builtin_amdgcn_update_dpp(0, __float_as_int(x), 0x111, 0xf, 0xf, true));  x += t;
    t = __int_as_float(__builtin_amdgcn_update_dpp(0, __float_as_int(x), 0x112, 0xf, 0xf, true));  x += t;
    t = __int_as_float(__builtin_amdgcn_update_dpp(0, __float_as_int(x), 0x114, 0xf, 0xf, true));  x += t;
    t = __int_as_float(__builtin_amdgcn_update_dpp(0, __float_as_int(x), 0x118, 0xf, 0xf, true));  x += t;
    t = __int_as_float(__builtin_amdgcn_update_dpp(0, __float_as_int(x), 0x142, 0xa, 0xf, false)); x += t;
    t = __int_as_float(__builtin_amdgcn_update_dpp(0, __float_as_int(x), 0x143, 0xc, 0xf, false)); x += t;
    return __int_as_float(__builtin_amdgcn_readlane(__float_as_int(x), 63));
}

__device__ __forceinline__ int wave_isum_dpp(int x) {
    int t;
    t = __builtin_amdgcn_update_dpp(0, x, 0x111, 0xf, 0xf, true);  x += t;
    t = __builtin_amdgcn_update_dpp(0, x, 0x112, 0xf, 0xf, true);  x += t;
    t = __builtin_amdgcn_update_dpp(0, x, 0x114, 0xf, 0xf, true);  x += t;
    t = __builtin_amdgcn_update_dpp(0, x, 0x118, 0xf, 0xf, true);  x += t;
    t = __builtin_amdgcn_update_dpp(0, x, 0x142, 0xa, 0xf, false); x += t;
    t = __builtin_amdgcn_update_dpp(0, x, 0x143, 0xc, 0xf, false); x += t;
    return __builtin_amdgcn_readlane(x, 63);
}

// min: identity = INT_MAX supplied as `old` with bound_ctrl=false so invalid
// source lanes / masked rows contribute INT_MAX (harmless for min).
__device__ __forceinline__ int wave_imin_dpp(int x) {
    const int I = 0x7fffffff;
    int t;
    t = __builtin_amdgcn_update_dpp(I, x, 0x111, 0xf, 0xf, false); x = min(x, t);
    t = __builtin_amdgcn_update_dpp(I, x, 0x112, 0xf, 0xf, false); x = min(x, t);
    t = __builtin_amdgcn_update_dpp(I, x, 0x114, 0xf, 0xf, false); x = min(x, t);
    t = __builtin_amdgcn_update_dpp(I, x, 0x118, 0xf, 0xf, false); x = min(x, t);
    t = __builtin_amdgcn_update_dpp(I, x, 0x142, 0xa, 0xf, false); x = min(x, t);
    t = __builtin_amdgcn_update_dpp(I, x, 0x143, 0xc, 0xf, false); x = min(x, t);
    return __builtin_amdgcn_readlane(x, 63);
}

// ---------------------------------------------------------------------------
// Kernel A (1024 thr): one pass over labels, per-thread register histogram +
// per-class min index; ALL wave reductions on the VALU via DPP (the previous
// __shfl_xor version put 84 DS ops x 16 waves on ONE CU's DS pipe ~ 3.5 us).
// Then 12 waves compute the 3 anchor-row inverse norms (DPP reduce).
// ---------------------------------------------------------------------------
__global__ __launch_bounds__(1024) void prep_kernel(
    const int* __restrict__ label,
    const float* __restrict__ s_t,
    const float* __restrict__ s_v,
    const float* __restrict__ s_a,
    int B, int D, float* __restrict__ ws)
{
    const int tid  = threadIdx.x;
    const int w    = tid >> 6;
    const int lane = tid & 63;

    int cnt[NCLS];
    int mn[NCLS];
#pragma unroll
    for (int k = 0; k < NCLS; ++k) { cnt[k] = 0; mn[k] = 0x7fffffff; }

    const int4* lab4 = (const int4*)label;
    const int n4 = B >> 2;
    for (int j = tid; j < n4; j += 1024) {
        int4 L = lab4[j];
        const int base = j << 2;
        int ls[4] = { L.x, L.y, L.z, L.w };
#pragma unroll
        for (int e = 0; e < 4; ++e) {
#pragma unroll
            for (int k = 0; k < NCLS; ++k) {
                if (ls[e] == k) { cnt[k]++; mn[k] = min(mn[k], base + e); }
            }
        }
    }
    for (int i = (n4 << 2) + tid; i < B; i += 1024) {
        int l = label[i];
#pragma unroll
        for (int k = 0; k < NCLS; ++k)
            if (l == k) { cnt[k]++; mn[k] = min(mn[k], i); }
    }

    // wave-level reduce on VALU (DPP), results uniform per wave
#pragma unroll
    for (int k = 0; k < NCLS; ++k) {
        cnt[k] = wave_isum_dpp(cnt[k]);
        mn[k]  = wave_imin_dpp(mn[k]);
    }

    __shared__ int   s_cnt[16][NCLS], s_mn[16][NCLS];
    __shared__ int   s_anchor;
    __shared__ float s_norm[12];
    if (lane == 0) {
#pragma unroll
        for (int k = 0; k < NCLS; ++k) { s_cnt[w][k] = cnt[k]; s_mn[w][k] = mn[k]; }
    }
    __syncthreads();

    if (tid == 0) {
        int hist[NCLS], mini[NCLS];
#pragma unroll
        for (int k = 0; k < NCLS; ++k) {
            int hc = 0, mc = 0x7fffffff;
            for (int q = 0; q < 16; ++q) { hc += s_cnt[q][k]; mc = min(mc, s_mn[q][k]); }
            hist[k] = hc; mini[k] = mc;
        }
        // jnp.argmax(counts > 1): first class with count>1, else 0
        int c = 0;
#pragma unroll
        for (int k = NCLS - 1; k >= 0; --k) if (hist[k] > 1) c = k;
        s_anchor = mini[c];

        Hdr* h = (Hdr*)ws;
        h->anchor  = mini[c];
        h->a_cls   = c;
        float pn   = (float)hist[c];
        h->pos_num = pn;
        h->neg_num = (float)B - pn;
    }
    __syncthreads();

    // inverse norms of the 3 anchor rows: wave w<12 -> row w>>2, quarter w&3
    const int anchor = s_anchor;
    if (w < 12) {
        const int rw = w >> 2, qw = w & 3;
        const float* src = (rw == 0) ? s_t : (rw == 1) ? s_v : s_a;
        const float4* row = (const float4*)(src + (size_t)anchor * D);
        const int nvec = D >> 2;
        float s = 0.f;
        for (int j = qw * 64 + lane; j < nvec; j += 256) {
            float4 x = row[j];
            s += dot4(x, x);
        }
        s = wave_fsum_dpp(s);
        if (lane == 0) s_norm[w] = s;
    }
    __syncthreads();
    if (tid < 3)
        ((float*)ws)[4 + tid] = rsqrtf(s_norm[4 * tid] + s_norm[4 * tid + 1] +
                                       s_norm[4 * tid + 2] + s_norm[4 * tid + 3]);
}

// ---------------------------------------------------------------------------
// Kernel B (unchanged from round 7 — validated): one wave per row, zero LDS,
// zero barriers, zero DS ops. 24 independent float4 loads fully unrolled,
// 36 dot4s, 4 DPP wave-reductions, lane 0 writes the row's (pos,neg) partial.
// ---------------------------------------------------------------------------
__global__ __launch_bounds__(256) void main_kernel(
    const int* __restrict__ label,
    const float* __restrict__ s_t,
    const float* __restrict__ s_v,
    const float* __restrict__ s_a,
    int B, int D, float* __restrict__ ws)
{
    const Hdr* h = (const Hdr*)ws;
    float2* partials = (float2*)(ws + 16);

    const int lane = threadIdx.x & 63;
    const int r    = blockIdx.x * 4 + (threadIdx.x >> 6);   // wave id == row
    if (r >= B) return;

    const int anchor = h->anchor;
    const int lab    = label[r];

    const float4* rt = (const float4*)(s_t + (size_t)r * D);
    const float4* rv = (const float4*)(s_v + (size_t)r * D);
    const float4* ra = (const float4*)(s_a + (size_t)r * D);
    const float4* at = (const float4*)(s_t + (size_t)anchor * D);
    const float4* av = (const float4*)(s_v + (size_t)anchor * D);
    const float4* aa = (const float4*)(s_a + (size_t)anchor * D);

    float dt_a = 0.f, dt_v = 0.f, sq_t = 0.f;
    float dv_t = 0.f, dv_a = 0.f, sq_v = 0.f;
    float da_t = 0.f, da_v = 0.f, sq_a = 0.f;

    const int nvec = D >> 2;
    if (nvec == 256) {
        float4 T[4], V[4], A[4], BT[4], BV[4], BA[4];
#pragma unroll
        for (int it = 0; it < 4; ++it) {
            const int j = lane + (it << 6);
            T[it]  = rt[j];  V[it]  = rv[j];  A[it]  = ra[j];
            BT[it] = at[j];  BV[it] = av[j];  BA[it] = aa[j];
        }
#pragma unroll
        for (int it = 0; it < 4; ++it) {
            dt_a += dot4(T[it], BA[it]);  dt_v += dot4(T[it], BV[it]);  sq_t += dot4(T[it], T[it]);
            dv_t += dot4(V[it], BT[it]);  dv_a += dot4(V[it], BA[it]);  sq_v += dot4(V[it], V[it]);
            da_t += dot4(A[it], BT[it]);  da_v += dot4(A[it], BV[it]);  sq_a += dot4(A[it], A[it]);
        }
    } else {
        for (int j = lane; j < nvec; j += 64) {
            float4 t  = rt[j], v  = rv[j], a  = ra[j];
            float4 bt = at[j], bv = av[j], ba = aa[j];
            dt_a += dot4(t, ba);  dt_v += dot4(t, bv);  sq_t += dot4(t, t);
            dv_t += dot4(v, bt);  dv_a += dot4(v, ba);  sq_v += dot4(v, v);
            da_t += dot4(a, bt);  da_v += dot4(a, bv);  sq_a += dot4(a, a);
        }
    }

    const float inv_t = rsqrtf(wave_fsum_dpp(sq_t));
    const float inv_v = rsqrtf(wave_fsum_dpp(sq_v));
    const float inv_a = rsqrtf(wave_fsum_dpp(sq_a));

    float c = inv_t * (dt_a * h->inv_aa + dt_v * h->inv_av)
            + inv_v * (dv_t * h->inv_at + dv_a * h->inv_aa)
            + inv_a * (da_t * h->inv_at + da_v * h->inv_av);
    const float rowtot = wave_fsum_dpp(c);

    if (lane == 0) {
        bool isPos = (lab == h->a_cls) && (r != anchor);
        bool isNeg = (lab != h->a_cls);
        partials[r] = make_float2(isPos ? rowtot : 0.f, isNeg ? rowtot : 0.f);
    }
}

// ---------------------------------------------------------------------------
// Kernel C: deterministic reduction of B partial pairs -> scalar loss.
// float4 loads (2 partials each), DPP wave reduce, tiny LDS combine.
// loss = (6 - pos_total/pos_num + neg_total/neg_num) / 3
// ---------------------------------------------------------------------------
__global__ __launch_bounds__(1024) void finish_kernel(
    const float* __restrict__ ws, int B, float* __restrict__ out)
{
    const Hdr* h = (const Hdr*)ws;
    const float4* p4 = (const float4*)(ws + 16);   // (pos,neg,pos,neg)

    float p = 0.f, n = 0.f;
    const int n4 = B >> 1;                         // float4 count (B even)
    for (int j = threadIdx.x; j < n4; j += 1024) {
        float4 x = p4[j];
        p += x.x + x.z;
        n += x.y + x.w;
    }
    p = wave_fsum_dpp(p);
    n = wave_fsum_dpp(n);

    __shared__ float pp[16], nn[16];
    const int w = threadIdx.x >> 6, lane = threadIdx.x & 63;
    if (lane == 0) { pp[w] = p; nn[w] = n; }
    __syncthreads();
    if (threadIdx.x == 0) {
        float P = 0.f, N = 0.f;
#pragma unroll
        for (int k = 0; k < 16; ++k) { P += pp[k]; N += nn[k]; }
        out[0] = (6.0f - P / h->pos_num + N / h->neg_num) / 3.0f;
    }
}

extern "C" void kernel_launch(void* const* d_in, const int* in_sizes, int n_in,
                              void* d_out, int out_size, void* d_ws, size_t ws_size,
                              hipStream_t stream) {
    const int*   label = (const int*)d_in[0];
    const float* s_t   = (const float*)d_in[1];
    const float* s_v   = (const float*)d_in[2];
    const float* s_a   = (const float*)d_in[3];

    const int B = in_sizes[0];
    const int D = in_sizes[1] / B;   // 1024

    float* ws  = (float*)d_ws;
    float* out = (float*)d_out;

    const int nblocks = (B + 3) / 4;   // one wave per row, 4 waves per block

    prep_kernel<<<1, 1024, 0, stream>>>(label, s_t, s_v, s_a, B, D, ws);
    main_kernel<<<nblocks, 256, 0, stream>>>(label, s_t, s_v, s_a, B, D, ws);
    finish_kernel<<<1, 1024, 0, stream>>>(ws, B, out);
}

// Round 9
// 29.716 us; speedup vs baseline: 4.9708x; 1.0208x over previous
//
#include <hip/hip_runtime.h>

#define NCLS 7

// ws layout (4-byte slots):
//   [0] int   anchor        [1] int   a_cls
//   [2] float pos_num       [3] float neg_num
//   [4] float inv_norm(anc_t) [5] inv_norm(anc_v) [6] inv_norm(anc_a)
//   [7..15] pad
//   [16..]   per-row partials: float2 (pos, neg)
struct Hdr {
    int   anchor;
    int   a_cls;
    float pos_num;
    float neg_num;
    float inv_at;
    float inv_av;
    float inv_aa;
    int   pad;
};

__device__ __forceinline__ float dot4(float4 a, float4 b) {
    return a.x * b.x + a.y * b.y + a.z * b.z + a.w * b.w;
}

// ---- Wave64 reductions on the VALU pipe via DPP (no DS ops) ---------------
__device__ __forceinline__ float wave_fsum_dpp(float x) {
    float t;
    t = __int_as_float(__builtin_amdgcn_update_dpp(0, __float_as_int(x), 0x111, 0xf, 0xf, true));  x += t;
    t = __int_as_float(__builtin_amdgcn_update_dpp(0, __float_as_int(x), 0x112, 0xf, 0xf, true));  x += t;
    t = __int_as_float(__builtin_amdgcn_update_dpp(0, __float_as_int(x), 0x114, 0xf, 0xf, true));  x += t;
    t = __int_as_float(__builtin_amdgcn_update_dpp(0, __float_as_int(x), 0x118, 0xf, 0xf, true));  x += t;
    t = __int_as_float(__builtin_amdgcn_update_dpp(0, __float_as_int(x), 0x142, 0xa, 0xf, false)); x += t;
    t = __int_as_float(__builtin_amdgcn_update_dpp(0, __float_as_int(x), 0x143, 0xc, 0xf, false)); x += t;
    return __int_as_float(__builtin_amdgcn_readlane(__float_as_int(x), 63));
}

__device__ __forceinline__ int wave_isum_dpp(int x) {
    int t;
    t = __builtin_amdgcn_update_dpp(0, x, 0x111, 0xf, 0xf, true);  x += t;
    t = __builtin_amdgcn_update_dpp(0, x, 0x112, 0xf, 0xf, true);  x += t;
    t = __builtin_amdgcn_update_dpp(0, x, 0x114, 0xf, 0xf, true);  x += t;
    t = __builtin_amdgcn_update_dpp(0, x, 0x118, 0xf, 0xf, true);  x += t;
    t = __builtin_amdgcn_update_dpp(0, x, 0x142, 0xa, 0xf, false); x += t;
    t = __builtin_amdgcn_update_dpp(0, x, 0x143, 0xc, 0xf, false); x += t;
    return __builtin_amdgcn_readlane(x, 63);
}

__device__ __forceinline__ int wave_imin_dpp(int x) {
    const int I = 0x7fffffff;
    int t;
    t = __builtin_amdgcn_update_dpp(I, x, 0x111, 0xf, 0xf, false); x = min(x, t);
    t = __builtin_amdgcn_update_dpp(I, x, 0x112, 0xf, 0xf, false); x = min(x, t);
    t = __builtin_amdgcn_update_dpp(I, x, 0x114, 0xf, 0xf, false); x = min(x, t);
    t = __builtin_amdgcn_update_dpp(I, x, 0x118, 0xf, 0xf, false); x = min(x, t);
    t = __builtin_amdgcn_update_dpp(I, x, 0x142, 0xa, 0xf, false); x = min(x, t);
    t = __builtin_amdgcn_update_dpp(I, x, 0x143, 0xc, 0xf, false); x = min(x, t);
    return __builtin_amdgcn_readlane(x, 63);
}

// ---------------------------------------------------------------------------
// Kernel A (1024 thr, unchanged from r8): one pass over labels, per-thread
// register histogram + per-class min index; DPP reductions (VALU pipe).
// Then 12 waves compute the 3 anchor-row inverse norms.
// ---------------------------------------------------------------------------
__global__ __launch_bounds__(1024) void prep_kernel(
    const int* __restrict__ label,
    const float* __restrict__ s_t,
    const float* __restrict__ s_v,
    const float* __restrict__ s_a,
    int B, int D, float* __restrict__ ws)
{
    const int tid  = threadIdx.x;
    const int w    = tid >> 6;
    const int lane = tid & 63;

    int cnt[NCLS];
    int mn[NCLS];
#pragma unroll
    for (int k = 0; k < NCLS; ++k) { cnt[k] = 0; mn[k] = 0x7fffffff; }

    const int4* lab4 = (const int4*)label;
    const int n4 = B >> 2;
    for (int j = tid; j < n4; j += 1024) {
        int4 L = lab4[j];
        const int base = j << 2;
        int ls[4] = { L.x, L.y, L.z, L.w };
#pragma unroll
        for (int e = 0; e < 4; ++e) {
#pragma unroll
            for (int k = 0; k < NCLS; ++k) {
                if (ls[e] == k) { cnt[k]++; mn[k] = min(mn[k], base + e); }
            }
        }
    }
    for (int i = (n4 << 2) + tid; i < B; i += 1024) {
        int l = label[i];
#pragma unroll
        for (int k = 0; k < NCLS; ++k)
            if (l == k) { cnt[k]++; mn[k] = min(mn[k], i); }
    }

#pragma unroll
    for (int k = 0; k < NCLS; ++k) {
        cnt[k] = wave_isum_dpp(cnt[k]);
        mn[k]  = wave_imin_dpp(mn[k]);
    }

    __shared__ int   s_cnt[16][NCLS], s_mn[16][NCLS];
    __shared__ int   s_anchor;
    __shared__ float s_norm[12];
    if (lane == 0) {
#pragma unroll
        for (int k = 0; k < NCLS; ++k) { s_cnt[w][k] = cnt[k]; s_mn[w][k] = mn[k]; }
    }
    __syncthreads();

    if (tid == 0) {
        int hist[NCLS], mini[NCLS];
#pragma unroll
        for (int k = 0; k < NCLS; ++k) {
            int hc = 0, mc = 0x7fffffff;
            for (int q = 0; q < 16; ++q) { hc += s_cnt[q][k]; mc = min(mc, s_mn[q][k]); }
            hist[k] = hc; mini[k] = mc;
        }
        // jnp.argmax(counts > 1): first class with count>1, else 0
        int c = 0;
#pragma unroll
        for (int k = NCLS - 1; k >= 0; --k) if (hist[k] > 1) c = k;
        s_anchor = mini[c];

        Hdr* h = (Hdr*)ws;
        h->anchor  = mini[c];
        h->a_cls   = c;
        float pn   = (float)hist[c];
        h->pos_num = pn;
        h->neg_num = (float)B - pn;
    }
    __syncthreads();

    const int anchor = s_anchor;
    if (w < 12) {
        const int rw = w >> 2, qw = w & 3;
        const float* src = (rw == 0) ? s_t : (rw == 1) ? s_v : s_a;
        const float4* row = (const float4*)(src + (size_t)anchor * D);
        const int nvec = D >> 2;
        float s = 0.f;
        for (int j = qw * 64 + lane; j < nvec; j += 256) {
            float4 x = row[j];
            s += dot4(x, x);
        }
        s = wave_fsum_dpp(s);
        if (lane == 0) s_norm[w] = s;
    }
    __syncthreads();
    if (tid < 3)
        ((float*)ws)[4 + tid] = rsqrtf(s_norm[4 * tid] + s_norm[4 * tid + 1] +
                                       s_norm[4 * tid + 2] + s_norm[4 * tid + 3]);
}

// ---------------------------------------------------------------------------
// Kernel B: one wave per row, zero LDS/DS, but LOW-VGPR / MAX-OCCUPANCY shape
// (r8 post-mortem: the fully-unrolled 24-float4 version cost ~130 VGPR ->
// 2-3 waves/SIMD -> the 8192-wave grid ran in 3-4 thin batches with exposed
// HBM latency at every transition). Here: unroll-1 loop, 6 float4 live,
// ~50 VGPR, __launch_bounds__(256,8) -> 8 waves/SIMD -> ALL waves resident,
// 192 KB outstanding per CU -> pure memory-service bound (copy-bench shape).
// ---------------------------------------------------------------------------
__global__ __launch_bounds__(256, 8) void main_kernel(
    const int* __restrict__ label,
    const float* __restrict__ s_t,
    const float* __restrict__ s_v,
    const float* __restrict__ s_a,
    int B, int D, float* __restrict__ ws)
{
    const Hdr* h = (const Hdr*)ws;
    float2* partials = (float2*)(ws + 16);

    const int lane = threadIdx.x & 63;
    const int r    = blockIdx.x * 4 + (threadIdx.x >> 6);   // wave id == row
    if (r >= B) return;

    const int anchor = h->anchor;
    const int lab    = label[r];

    const float4* rt = (const float4*)(s_t + (size_t)r * D);
    const float4* rv = (const float4*)(s_v + (size_t)r * D);
    const float4* ra = (const float4*)(s_a + (size_t)r * D);
    const float4* at = (const float4*)(s_t + (size_t)anchor * D);
    const float4* av = (const float4*)(s_v + (size_t)anchor * D);
    const float4* aa = (const float4*)(s_a + (size_t)anchor * D);

    float dt_a = 0.f, dt_v = 0.f, sq_t = 0.f;
    float dv_t = 0.f, dv_a = 0.f, sq_v = 0.f;
    float da_t = 0.f, da_v = 0.f, sq_a = 0.f;

    const int nvec = D >> 2;
#pragma unroll 1
    for (int j = lane; j < nvec; j += 64) {
        float4 t  = rt[j], v  = rv[j], a  = ra[j];
        float4 bt = at[j], bv = av[j], ba = aa[j];
        dt_a += dot4(t, ba);  dt_v += dot4(t, bv);  sq_t += dot4(t, t);
        dv_t += dot4(v, bt);  dv_a += dot4(v, ba);  sq_v += dot4(v, v);
        da_t += dot4(a, bt);  da_v += dot4(a, bv);  sq_a += dot4(a, a);
    }

    const float inv_t = rsqrtf(wave_fsum_dpp(sq_t));
    const float inv_v = rsqrtf(wave_fsum_dpp(sq_v));
    const float inv_a = rsqrtf(wave_fsum_dpp(sq_a));

    float c = inv_t * (dt_a * h->inv_aa + dt_v * h->inv_av)
            + inv_v * (dv_t * h->inv_at + dv_a * h->inv_aa)
            + inv_a * (da_t * h->inv_at + da_v * h->inv_av);
    const float rowtot = wave_fsum_dpp(c);

    if (lane == 0) {
        bool isPos = (lab == h->a_cls) && (r != anchor);
        bool isNeg = (lab != h->a_cls);
        partials[r] = make_float2(isPos ? rowtot : 0.f, isNeg ? rowtot : 0.f);
    }
}

// ---------------------------------------------------------------------------
// Kernel C (unchanged from r8): deterministic reduction of B partial pairs.
// loss = (6 - pos_total/pos_num + neg_total/neg_num) / 3
// ---------------------------------------------------------------------------
__global__ __launch_bounds__(1024) void finish_kernel(
    const float* __restrict__ ws, int B, float* __restrict__ out)
{
    const Hdr* h = (const Hdr*)ws;
    const float4* p4 = (const float4*)(ws + 16);   // (pos,neg,pos,neg)

    float p = 0.f, n = 0.f;
    const int n4 = B >> 1;                         // float4 count (B even)
    for (int j = threadIdx.x; j < n4; j += 1024) {
        float4 x = p4[j];
        p += x.x + x.z;
        n += x.y + x.w;
    }
    p = wave_fsum_dpp(p);
    n = wave_fsum_dpp(n);

    __shared__ float pp[16], nn[16];
    const int w = threadIdx.x >> 6, lane = threadIdx.x & 63;
    if (lane == 0) { pp[w] = p; nn[w] = n; }
    __syncthreads();
    if (threadIdx.x == 0) {
        float P = 0.f, N = 0.f;
#pragma unroll
        for (int k = 0; k < 16; ++k) { P += pp[k]; N += nn[k]; }
        out[0] = (6.0f - P / h->pos_num + N / h->neg_num) / 3.0f;
    }
}

extern "C" void kernel_launch(void* const* d_in, const int* in_sizes, int n_in,
                              void* d_out, int out_size, void* d_ws, size_t ws_size,
                              hipStream_t stream) {
    const int*   label = (const int*)d_in[0];
    const float* s_t   = (const float*)d_in[1];
    const float* s_v   = (const float*)d_in[2];
    const float* s_a   = (const float*)d_in[3];

    const int B = in_sizes[0];
    const int D = in_sizes[1] / B;   // 1024

    float* ws  = (float*)d_ws;
    float* out = (float*)d_out;

    const int nblocks = (B + 3) / 4;   // one wave per row, 4 waves per block

    prep_kernel<<<1, 1024, 0, stream>>>(label, s_t, s_v, s_a, B, D, ws);
    main_kernel<<<nblocks, 256, 0, stream>>>(label, s_t, s_v, s_a, B, D, ws);
    finish_kernel<<<1, 1024, 0, stream>>>(ws, B, out);
}